// Round 1
// baseline (87.577 us; speedup 1.0000x reference)
//
#include <hip/hip_runtime.h>
#include <hip/hip_bf16.h>

// CrossNetLayer: h = x @ W_enc + b_enc; then 4x cross layers
//   s = x_l . w_l   (per row); x_l += x0 * s + b_l
// B = D = H = 1024, DEPTH = 4. All fp32 in/out; GEMM internally f16 MFMA.

#define B_SZ 1024
#define D_SZ 1024
#define H_SZ 1024
#define DEPTH 4

typedef _Float16 half4_t __attribute__((ext_vector_type(4)));
typedef _Float16 half8_t __attribute__((ext_vector_type(8)));
typedef float float16_t __attribute__((ext_vector_type(16)));

typedef const __attribute__((address_space(1))) unsigned int* gas_ptr;
typedef __attribute__((address_space(3))) unsigned int* las_ptr;

__device__ __forceinline__ void async_copy16(const void* g, void* l) {
    // 16 B per lane, LDS dest = wave-uniform base + lane*16
    __builtin_amdgcn_global_load_lds((gas_ptr)g, (las_ptr)l, 16, 0, 0);
}

// ---------------------------------------------------------------------------
// Kernel 1: prep. Blocks 0..255: transpose-convert W (fp32 [k][n]) ->
// Wt (f16 [n][k]). Blocks 256..511: convert x (fp32) -> xh (f16).
// ---------------------------------------------------------------------------
__global__ __launch_bounds__(256) void prep_kernel(
        const float* __restrict__ x, const float* __restrict__ W,
        _Float16* __restrict__ xh, _Float16* __restrict__ Wt) {
    const int b = blockIdx.x;
    const int t = threadIdx.x;
    if (b < 256) {
        // 64x64 tile transpose via LDS. S[k_local][n_local], pad to 65 to
        // break bank alignment on the transposed reads.
        __shared__ float S[64][65];
        const int k0 = (b >> 4) << 6;
        const int n0 = (b & 15) << 6;
#pragma unroll
        for (int i = 0; i < 4; ++i) {
            int idx = (i << 8) + t;        // 0..1023
            int r = idx >> 4;              // k-local 0..63
            int c4 = idx & 15;             // float4 group along n
            float4 v = *(const float4*)(W + (size_t)(k0 + r) * H_SZ + n0 + (c4 << 2));
            S[r][(c4 << 2) + 0] = v.x;
            S[r][(c4 << 2) + 1] = v.y;
            S[r][(c4 << 2) + 2] = v.z;
            S[r][(c4 << 2) + 3] = v.w;
        }
        __syncthreads();
#pragma unroll
        for (int i = 0; i < 4; ++i) {
            int idx = (i << 8) + t;
            int n = idx >> 4;              // n-local 0..63
            int c4 = idx & 15;             // float4 group along k
            int k = c4 << 2;
            half4_t o;
            o.x = (_Float16)S[k + 0][n];
            o.y = (_Float16)S[k + 1][n];
            o.z = (_Float16)S[k + 2][n];
            o.w = (_Float16)S[k + 3][n];
            *(half4_t*)(Wt + (size_t)(n0 + n) * D_SZ + k0 + k) = o;
        }
    } else {
        const int base = (b - 256) * 4096;
#pragma unroll
        for (int i = 0; i < 4; ++i) {
            int off = base + (((i << 8) + t) << 2);
            float4 v = *(const float4*)(x + off);
            half4_t o;
            o.x = (_Float16)v.x; o.y = (_Float16)v.y;
            o.z = (_Float16)v.z; o.w = (_Float16)v.w;
            *(half4_t*)(xh + off) = o;
        }
    }
}

// ---------------------------------------------------------------------------
// Kernel 2: GEMM h = xh @ Wt^T (Wt is [n][k] f16), fp32 out -> d_out.
// BM=BN=64, BK=32. 256 thr = 4 waves, each wave one 32x32 mfma tile.
// global_load_lds 16B staging (wave-uniform LDS base + lane*16 -> unpadded).
// ---------------------------------------------------------------------------
__global__ __launch_bounds__(256) void gemm_kernel(
        const _Float16* __restrict__ xh, const _Float16* __restrict__ Wt,
        float* __restrict__ h) {
    __shared__ _Float16 As[64 * 32];   // [m][k]
    __shared__ _Float16 Bs[64 * 32];   // [n][k]
    const int tid  = threadIdx.x;
    const int w    = tid >> 6;
    const int lane = tid & 63;
    const int m0 = blockIdx.y << 6;
    const int n0 = blockIdx.x << 6;
    const int wm = (w >> 1) << 5;      // wave row offset: 0/32
    const int wn = (w & 1) << 5;       // wave col offset: 0/32

    // staging: thread tid covers As element (tid/4, (tid%4)*8), 8 halfs = 16 B
    const int srow = tid >> 2;
    const int scol = (tid & 3) << 3;
    const _Float16* aSrc = xh + (size_t)(m0 + srow) * D_SZ + scol;
    const _Float16* bSrc = Wt + (size_t)(n0 + srow) * D_SZ + scol;
    _Float16* aDst = As + (w << 9);    // w*512 halfs = w*1024 B
    _Float16* bDst = Bs + (w << 9);

    // fragment addresses (A: row=l%32, k=(l/32)*8+i ; B: col=l%32, same k)
    const int arow = wm + (lane & 31);
    const int brow = wn + (lane & 31);
    const int koff = (lane >> 5) << 3; // 0 or 8

    float16_t acc;
#pragma unroll
    for (int i = 0; i < 16; ++i) acc[i] = 0.0f;

    for (int k0 = 0; k0 < D_SZ; k0 += 32) {
        async_copy16(aSrc + k0, aDst);
        async_copy16(bSrc + k0, bDst);
        __syncthreads();
#pragma unroll
        for (int kc = 0; kc < 32; kc += 16) {
            half8_t af = *(const half8_t*)(As + arow * 32 + kc + koff);
            half8_t bf = *(const half8_t*)(Bs + brow * 32 + kc + koff);
            acc = __builtin_amdgcn_mfma_f32_32x32x16_f16(af, bf, acc, 0, 0, 0);
        }
        __syncthreads();
    }

    // C/D layout: col = lane&31, row = (r&3) + 8*(r>>2) + 4*(lane>>5)
    const int col = n0 + wn + (lane & 31);
    const int rbase = m0 + wm + ((lane >> 5) << 2);
#pragma unroll
    for (int r = 0; r < 16; ++r) {
        int row = rbase + (r & 3) + ((r >> 2) << 3);
        h[(size_t)row * H_SZ + col] = acc[r];
    }
}

// ---------------------------------------------------------------------------
// Kernel 3: CrossNet, one block per row, in-place on d_out. Fuses b_enc add.
// ---------------------------------------------------------------------------
__global__ __launch_bounds__(256) void crossnet_kernel(
        float* __restrict__ h, const float* __restrict__ b_enc,
        const float* __restrict__ ws, const float* __restrict__ bs) {
    const int row = blockIdx.x;
    const int t = threadIdx.x;
    float* hr = h + (size_t)row * H_SZ;

    float4 hv = *(const float4*)(hr + (t << 2));
    float4 be = *(const float4*)(b_enc + (t << 2));
    float x0[4] = {hv.x + be.x, hv.y + be.y, hv.z + be.z, hv.w + be.w};
    float xl[4] = {x0[0], x0[1], x0[2], x0[3]};

    __shared__ float red[4];
    __shared__ float sbc;

    for (int l = 0; l < DEPTH; ++l) {
        float4 wv = *(const float4*)(ws + l * H_SZ + (t << 2));
        float4 bv = *(const float4*)(bs + l * H_SZ + (t << 2));
        float p = xl[0] * wv.x + xl[1] * wv.y + xl[2] * wv.z + xl[3] * wv.w;
#pragma unroll
        for (int off = 32; off > 0; off >>= 1) p += __shfl_down(p, off, 64);
        if ((t & 63) == 0) red[t >> 6] = p;
        __syncthreads();
        if (t == 0) sbc = red[0] + red[1] + red[2] + red[3];
        __syncthreads();
        float s = sbc;
        xl[0] += x0[0] * s + bv.x;
        xl[1] += x0[1] * s + bv.y;
        xl[2] += x0[2] * s + bv.z;
        xl[3] += x0[3] * s + bv.w;
    }
    float4 o = {xl[0], xl[1], xl[2], xl[3]};
    *(float4*)(hr + (t << 2)) = o;
}

extern "C" void kernel_launch(void* const* d_in, const int* in_sizes, int n_in,
                              void* d_out, int out_size, void* d_ws, size_t ws_size,
                              hipStream_t stream) {
    const float* x     = (const float*)d_in[0];
    const float* W_enc = (const float*)d_in[1];
    const float* b_enc = (const float*)d_in[2];
    const float* ws    = (const float*)d_in[3];
    const float* bs    = (const float*)d_in[4];
    float* out = (float*)d_out;

    _Float16* xh = (_Float16*)d_ws;                 // 2 MB
    _Float16* Wt = xh + (size_t)B_SZ * D_SZ;        // 2 MB

    prep_kernel<<<512, 256, 0, stream>>>(x, W_enc, xh, Wt);
    dim3 grid(H_SZ / 64, B_SZ / 64);
    gemm_kernel<<<grid, 256, 0, stream>>>(xh, Wt, out);
    crossnet_kernel<<<B_SZ, 256, 0, stream>>>(out, b_enc, ws, bs);
}

// Round 2
// 82.757 us; speedup vs baseline: 1.0582x; 1.0582x over previous
//
#include <hip/hip_runtime.h>
#include <hip/hip_bf16.h>

// CrossNetLayer: h = x @ W_enc + b_enc; then 4x cross layers
//   s = x_l . w_l (per row); x_l += x0 * s + b_l
// B = D = H = 1024, DEPTH = 4. fp32 in/out; GEMM internally f16 MFMA.
//
// R2: gemm re-tiled 32x64/block, 8 waves of 16x16x32 MFMA, grid 512 =
// 2 blocks/CU (16 waves/CU), double-buffered LDS w/ XOR bank swizzle,
// 1 barrier per K-iter. Crossnet: loop-invariant weight loads hoisted,
// 1 barrier per layer.

#define B_SZ 1024
#define D_SZ 1024
#define H_SZ 1024
#define DEPTH 4

typedef _Float16 half4_t __attribute__((ext_vector_type(4)));
typedef _Float16 half8_t __attribute__((ext_vector_type(8)));
typedef float floatx4_t __attribute__((ext_vector_type(4)));

typedef const __attribute__((address_space(1))) unsigned int* gas_ptr;
typedef __attribute__((address_space(3))) unsigned int* las_ptr;

__device__ __forceinline__ void async_copy16(const void* g, void* l) {
    // 16 B per lane; HW dest = wave-uniform base + lane*16
    __builtin_amdgcn_global_load_lds((gas_ptr)g, (las_ptr)l, 16, 0, 0);
}

// ---------------------------------------------------------------------------
// Kernel 1: prep. Blocks 0..255: transpose-convert W (fp32 [k][n]) ->
// Wt (f16 [n][k]). Blocks 256..511: convert x (fp32) -> xh (f16).
// ---------------------------------------------------------------------------
__global__ __launch_bounds__(256) void prep_kernel(
        const float* __restrict__ x, const float* __restrict__ W,
        _Float16* __restrict__ xh, _Float16* __restrict__ Wt) {
    const int b = blockIdx.x;
    const int t = threadIdx.x;
    if (b < 256) {
        __shared__ float S[64][65];    // +1 pad: transposed reads conflict-free
        const int k0 = (b >> 4) << 6;
        const int n0 = (b & 15) << 6;
#pragma unroll
        for (int i = 0; i < 4; ++i) {
            int idx = (i << 8) + t;
            int r = idx >> 4;              // k-local 0..63
            int c4 = idx & 15;             // float4 group along n
            float4 v = *(const float4*)(W + (size_t)(k0 + r) * H_SZ + n0 + (c4 << 2));
            S[r][(c4 << 2) + 0] = v.x;
            S[r][(c4 << 2) + 1] = v.y;
            S[r][(c4 << 2) + 2] = v.z;
            S[r][(c4 << 2) + 3] = v.w;
        }
        __syncthreads();
#pragma unroll
        for (int i = 0; i < 4; ++i) {
            int idx = (i << 8) + t;
            int n = idx >> 4;              // n-local 0..63
            int c4 = idx & 15;
            int k = c4 << 2;
            half4_t o;
            o.x = (_Float16)S[k + 0][n];
            o.y = (_Float16)S[k + 1][n];
            o.z = (_Float16)S[k + 2][n];
            o.w = (_Float16)S[k + 3][n];
            *(half4_t*)(Wt + (size_t)(n0 + n) * D_SZ + k0 + k) = o;
        }
    } else {
        const int base = (b - 256) * 4096;
#pragma unroll
        for (int i = 0; i < 4; ++i) {
            int off = base + (((i << 8) + t) << 2);
            float4 v = *(const float4*)(x + off);
            half4_t o;
            o.x = (_Float16)v.x; o.y = (_Float16)v.y;
            o.z = (_Float16)v.z; o.w = (_Float16)v.w;
            *(half4_t*)(xh + off) = o;
        }
    }
}

// ---------------------------------------------------------------------------
// Kernel 2: GEMM h = xh @ Wt^T. BM=32, BN=64, BK=64. 512 thr = 8 waves,
// wave grid 2(m) x 4(n), one 16x16 tile per wave via mfma_f32_16x16x32_f16.
// grid (16,32) = 512 blocks = 2 blocks/CU. Double-buffered swizzled LDS.
// ---------------------------------------------------------------------------
__global__ __launch_bounds__(512) void gemm_kernel(
        const _Float16* __restrict__ xh, const _Float16* __restrict__ Wt,
        float* __restrict__ h) {
    // LDS: rows of 64 halfs = 8 chunks of 16 B. Physical chunk (r,c) holds
    // logical k-chunk c ^ (r&7)  -> fragment reads are 2-way (free).
    __shared__ _Float16 As[2][32 * 64];   // 4 KB / buf
    __shared__ _Float16 Bs[2][64 * 64];   // 8 KB / buf
    const int tid  = threadIdx.x;
    const int lane = tid & 63;
    const int w    = tid >> 6;            // 0..7
    const int m0 = blockIdx.y << 5;
    const int n0 = blockIdx.x << 6;
    const int wm = (w >> 2) << 4;         // 0 / 16
    const int wn = (w & 3) << 4;          // 0 / 16 / 32 / 48

    // staging: slot s = tid -> row r = s>>3, phys chunk c = s&7,
    // logical chunk = c ^ (r&7). Waves 0-3 stage A (256 slots); all stage B.
    const int sr = tid >> 3;
    const int sc = ((tid & 7) ^ (sr & 7)) << 3;  // half offset of 16B chunk
    const _Float16* aSrc = xh + (size_t)(m0 + (sr & 31)) * D_SZ + sc;
    const _Float16* bSrc = Wt + (size_t)(n0 + sr) * D_SZ + sc;

    // fragment geometry (16x16x32): A[m=lane&15][k=q*8+j], B symmetric.
    const int ra = wm + (lane & 15);
    const int rb = wn + (lane & 15);
    const int q  = lane >> 4;

    floatx4_t acc = {0.0f, 0.0f, 0.0f, 0.0f};

    // stage buffer 0
    if (tid < 256) async_copy16(aSrc, &As[0][tid << 3]);
    async_copy16(bSrc, &Bs[0][tid << 3]);

    for (int it = 0; it < 16; ++it) {
        __syncthreads();   // drains stage(it); all waves done reading buf[(it+1)&1]
        if (it + 1 < 16) {
            int k0 = (it + 1) << 6;
            int buf = (it + 1) & 1;
            if (tid < 256) async_copy16(aSrc + k0, &As[buf][tid << 3]);
            async_copy16(bSrc + k0, &Bs[buf][tid << 3]);
        }
        const _Float16* Ab = As[it & 1];
        const _Float16* Bb = Bs[it & 1];
#pragma unroll
        for (int kk = 0; kk < 2; ++kk) {
            int l = (kk << 2) + q;
            half8_t af = *(const half8_t*)(Ab + ra * 64 + ((l ^ (ra & 7)) << 3));
            half8_t bf = *(const half8_t*)(Bb + rb * 64 + ((l ^ (rb & 7)) << 3));
            acc = __builtin_amdgcn_mfma_f32_16x16x32_f16(af, bf, acc, 0, 0, 0);
        }
    }

    // C/D: col = lane&15, row = (lane>>4)*4 + reg
    const int col = n0 + wn + (lane & 15);
    const int row0 = m0 + wm + (q << 2);
#pragma unroll
    for (int r = 0; r < 4; ++r)
        h[(size_t)(row0 + r) * H_SZ + col] = acc[r];
}

// ---------------------------------------------------------------------------
// Kernel 3: CrossNet, one block per row, in-place on d_out. Fuses b_enc add.
// Weight loads hoisted (loop-invariant); 1 barrier per layer.
// ---------------------------------------------------------------------------
__global__ __launch_bounds__(256) void crossnet_kernel(
        float* __restrict__ h, const float* __restrict__ b_enc,
        const float* __restrict__ ws, const float* __restrict__ bs) {
    const int row = blockIdx.x;
    const int t = threadIdx.x;
    float* hr = h + (size_t)row * H_SZ;

    float4 hv = *(const float4*)(hr + (t << 2));
    float4 be = *(const float4*)(b_enc + (t << 2));
    // hoist all layer weights (independent of the recurrence)
    float4 wv[DEPTH], bv[DEPTH];
#pragma unroll
    for (int l = 0; l < DEPTH; ++l) {
        wv[l] = *(const float4*)(ws + l * H_SZ + (t << 2));
        bv[l] = *(const float4*)(bs + l * H_SZ + (t << 2));
    }
    float x0[4] = {hv.x + be.x, hv.y + be.y, hv.z + be.z, hv.w + be.w};
    float xl[4] = {x0[0], x0[1], x0[2], x0[3]};

    __shared__ float red[DEPTH][4];

#pragma unroll
    for (int l = 0; l < DEPTH; ++l) {
        float p = xl[0] * wv[l].x + xl[1] * wv[l].y + xl[2] * wv[l].z + xl[3] * wv[l].w;
#pragma unroll
        for (int off = 32; off > 0; off >>= 1) p += __shfl_down(p, off, 64);
        if ((t & 63) == 0) red[l][t >> 6] = p;
        __syncthreads();   // per-layer slots -> no WAR hazard, single barrier
        float s = red[l][0] + red[l][1] + red[l][2] + red[l][3];
        xl[0] += x0[0] * s + bv[l].x;
        xl[1] += x0[1] * s + bv[l].y;
        xl[2] += x0[2] * s + bv[l].z;
        xl[3] += x0[3] * s + bv[l].w;
    }
    float4 o = {xl[0], xl[1], xl[2], xl[3]};
    *(float4*)(hr + (t << 2)) = o;
}

extern "C" void kernel_launch(void* const* d_in, const int* in_sizes, int n_in,
                              void* d_out, int out_size, void* d_ws, size_t ws_size,
                              hipStream_t stream) {
    const float* x     = (const float*)d_in[0];
    const float* W_enc = (const float*)d_in[1];
    const float* b_enc = (const float*)d_in[2];
    const float* ws    = (const float*)d_in[3];
    const float* bs    = (const float*)d_in[4];
    float* out = (float*)d_out;

    _Float16* xh = (_Float16*)d_ws;                 // 2 MB
    _Float16* Wt = xh + (size_t)B_SZ * D_SZ;        // 2 MB

    prep_kernel<<<512, 256, 0, stream>>>(x, W_enc, xh, Wt);
    dim3 grid(H_SZ / 64, B_SZ / 32);                // (n-tiles, m-tiles)
    gemm_kernel<<<grid, 512, 0, stream>>>(xh, Wt, out);
    crossnet_kernel<<<B_SZ, 256, 0, stream>>>(out, b_enc, ws, bs);
}